// Round 1
// baseline (495.914 us; speedup 1.0000x reference)
//
#include <hip/hip_runtime.h>
#include <hip/hip_fp16.h>

#define IN_DIM  65536
#define OUT_DIM 65536
#define BATCH   1024
#define THREADS 1024

// ---------------------------------------------------------------------------
// Kernel 1: per-output-j gate coefficients.
// Each gate g(av,bv) = c0 + c1*av + c2*bv + c3*av*bv; fold softmax(weights[j])
// into 4 coefficients A0..A3 stored as float4 in workspace.
// ---------------------------------------------------------------------------
__global__ void coef_kernel(const float* __restrict__ w, float4* __restrict__ coef) {
    int j = blockIdx.x * blockDim.x + threadIdx.x;
    const float4* w4 = (const float4*)(w + (size_t)j * 16);
    float4 wa = w4[0], wb = w4[1], wc = w4[2], wd = w4[3];
    float nw[16] = {wa.x, wa.y, wa.z, wa.w,
                    wb.x, wb.y, wb.z, wb.w,
                    wc.x, wc.y, wc.z, wc.w,
                    wd.x, wd.y, wd.z, wd.w};
    float m = nw[0];
#pragma unroll
    for (int i = 1; i < 16; ++i) m = fmaxf(m, nw[i]);
    float s = 0.0f;
#pragma unroll
    for (int i = 0; i < 16; ++i) { nw[i] = expf(nw[i] - m); s += nw[i]; }
    float inv = 1.0f / s;
#pragma unroll
    for (int i = 0; i < 16; ++i) nw[i] *= inv;

    float A0 = nw[8] + nw[9] + nw[10] + nw[11] + nw[12] + nw[13] + nw[14] + nw[15];
    float A1 = nw[2] + nw[3] + nw[6] + nw[7] - nw[8] - nw[9] - nw[12] - nw[13];
    float A2 = nw[4] + nw[5] + nw[6] + nw[7] - nw[8] - nw[9] - nw[10] - nw[11];
    float A3 = nw[1] - nw[2] - nw[4] - 2.0f * nw[6] - nw[7]
             + nw[8] + 2.0f * nw[9] + nw[11] + nw[13] - nw[14];
    coef[j] = make_float4(A0, A1, A2, A3);
}

// ---------------------------------------------------------------------------
// Kernel 2: one block per batch row. Stage the full x-row as fp16 in 128 KB
// dynamic LDS (coalesced read of x), then random-gather av/bv from LDS and
// evaluate the bilinear form. Writes are fully coalesced float4.
// ---------------------------------------------------------------------------
__global__ void __launch_bounds__(THREADS, 1)
logic_main(const float* __restrict__ x, const float4* __restrict__ coef,
           const int* __restrict__ a, const int* __restrict__ b,
           float* __restrict__ out) {
    extern __shared__ __half xr16[];   // IN_DIM halves = 128 KB
    const int row = blockIdx.x;

    // --- stage row (coalesced float4 loads, half2 LDS writes) ---
    const float4* x4 = (const float4*)(x + (size_t)row * IN_DIM);
    __half2* xr2 = (__half2*)xr16;
    for (int t = threadIdx.x; t < IN_DIM / 4; t += THREADS) {
        float4 v = x4[t];
        xr2[2 * t + 0] = __floats2half2_rn(v.x, v.y);
        xr2[2 * t + 1] = __floats2half2_rn(v.z, v.w);
    }
    __syncthreads();

    // --- main loop: 4 outputs per thread-iteration ---
    const int4* a4 = (const int4*)a;
    const int4* b4 = (const int4*)b;
    float4* out4 = (float4*)(out + (size_t)row * OUT_DIM);
    for (int t = threadIdx.x; t < OUT_DIM / 4; t += THREADS) {
        int4 aj = a4[t];
        int4 bj = b4[t];
        float4 c0 = coef[4 * t + 0];
        float4 c1 = coef[4 * t + 1];
        float4 c2 = coef[4 * t + 2];
        float4 c3 = coef[4 * t + 3];
        float av0 = __half2float(xr16[aj.x]), bv0 = __half2float(xr16[bj.x]);
        float av1 = __half2float(xr16[aj.y]), bv1 = __half2float(xr16[bj.y]);
        float av2 = __half2float(xr16[aj.z]), bv2 = __half2float(xr16[bj.z]);
        float av3 = __half2float(xr16[aj.w]), bv3 = __half2float(xr16[bj.w]);
        float4 o;
        o.x = c0.x + av0 * c0.y + bv0 * (c0.z + av0 * c0.w);
        o.y = c1.x + av1 * c1.y + bv1 * (c1.z + av1 * c1.w);
        o.z = c2.x + av2 * c2.y + bv2 * (c2.z + av2 * c2.w);
        o.w = c3.x + av3 * c3.y + bv3 * (c3.z + av3 * c3.w);
        out4[t] = o;
    }
}

extern "C" void kernel_launch(void* const* d_in, const int* in_sizes, int n_in,
                              void* d_out, int out_size, void* d_ws, size_t ws_size,
                              hipStream_t stream) {
    const float* x = (const float*)d_in[0];
    const float* w = (const float*)d_in[1];
    const int*   a = (const int*)d_in[2];
    const int*   b = (const int*)d_in[3];
    float* out = (float*)d_out;
    float4* coef = (float4*)d_ws;   // OUT_DIM * 16 B = 1 MB scratch

    // Allow 128 KB dynamic LDS (gfx950 has 160 KB/CU). Idempotent; safe under
    // graph capture (host-side, no stream op).
    (void)hipFuncSetAttribute((const void*)logic_main,
                              hipFuncAttributeMaxDynamicSharedMemorySize,
                              IN_DIM * (int)sizeof(__half));

    coef_kernel<<<OUT_DIM / 256, 256, 0, stream>>>(w, coef);
    logic_main<<<BATCH, THREADS, IN_DIM * sizeof(__half), stream>>>(x, coef, a, b, out);
}